// Round 1
// baseline (489.205 us; speedup 1.0000x reference)
//
#include <hip/hip_runtime.h>
#include <math.h>

// Problem constants
#define BB 64
#define CCH 64
#define LL 8192
#define FF 4097
#define FP 4104   // padded row stride for spectra
#define M4 4096
#define NCH 13    // t-chunks per (b,enc): 13 chunks x 5 tiles x 64 t = 4160 >= 4097
#define TPB 5     // tiles (64 t each) per block

typedef __attribute__((ext_vector_type(8))) short short8;
typedef __attribute__((ext_vector_type(4))) float floatx4;

__device__ __forceinline__ short f2bf(float v) {
    union { float f; unsigned u; } cv; cv.f = v;
    unsigned r = (cv.u + 0x7fffu + ((cv.u >> 16) & 1u)) >> 16;
    return (short)r;
}

// ---------------- complex helpers ----------------
__device__ __forceinline__ float2 cadd(float2 a, float2 b){ return make_float2(a.x+b.x, a.y+b.y); }
__device__ __forceinline__ float2 csub(float2 a, float2 b){ return make_float2(a.x-b.x, a.y-b.y); }
__device__ __forceinline__ float2 cmul(float2 a, float2 b){ return make_float2(a.x*b.x-a.y*b.y, a.x*b.y+a.y*b.x); }
template<int SIGN> __device__ __forceinline__ float2 roti(float2 a){
    return (SIGN < 0) ? make_float2(a.y, -a.x) : make_float2(-a.y, a.x);
}
template<int SIGN>
__device__ __forceinline__ void dft4(float2& a, float2& b, float2& c, float2& d){
    float2 t0 = cadd(a,c), t1 = csub(a,c), t2 = cadd(b,d), t3 = roti<SIGN>(csub(b,d));
    a = cadd(t0,t2); b = cadd(t1,t3); c = csub(t0,t2); d = csub(t1,t3);
}

// DFT-16, natural order in and out, fully unrolled, constant twiddles.
template<int SIGN>
__device__ __forceinline__ void dft16(float2 v[16]){
    const float C1 = 0.9238795325112867f, S1 = 0.3826834323650898f, R2 = 0.7071067811865476f;
    const float sg = (SIGN < 0) ? -1.0f : 1.0f;
#pragma unroll
    for (int n1 = 0; n1 < 4; ++n1) dft4<SIGN>(v[n1], v[n1+4], v[n1+8], v[n1+12]);
    const float2 W1 = make_float2( C1, sg*S1);
    const float2 W2 = make_float2( R2, sg*R2);
    const float2 W3 = make_float2( S1, sg*C1);
    const float2 W6 = make_float2(-R2, sg*R2);
    const float2 W9 = make_float2(-C1, -sg*S1);
    v[5]  = cmul(v[5],  W1); v[6]  = cmul(v[6],  W2); v[7]  = cmul(v[7],  W3);
    v[9]  = cmul(v[9],  W2); v[10] = roti<SIGN>(v[10]); v[11] = cmul(v[11], W6);
    v[13] = cmul(v[13], W3); v[14] = cmul(v[14], W6); v[15] = cmul(v[15], W9);
#pragma unroll
    for (int k2 = 0; k2 < 4; ++k2) dft4<SIGN>(v[4*k2+0], v[4*k2+1], v[4*k2+2], v[4*k2+3]);
    float2 t[16];
#pragma unroll
    for (int k = 0; k < 16; ++k) t[k] = v[4*(k & 3) + (k >> 2)];
#pragma unroll
    for (int k = 0; k < 16; ++k) v[k] = t[k];
}

__device__ __forceinline__ void twiddle_pow(float2 v[16], float ang){
    float s, c; __sincosf(ang, &s, &c);
    float2 w = make_float2(c, s), t = w;
    v[1] = cmul(v[1], t);
#pragma unroll
    for (int j = 2; j < 16; ++j){ t = cmul(t, w); v[j] = cmul(v[j], t); }
}

template<int SIGN>
__device__ __forceinline__ void fft4096_regs(float2 v[16], float2* lds, int tid){
    const float TWO_PI = 6.283185307179586f;
    const float sg = (SIGN < 0) ? -1.0f : 1.0f;
    int n1 = tid & 15, hi = tid >> 4;
    dft16<SIGN>(v);
    twiddle_pow(v, sg * TWO_PI * (float)hi * (1.0f/256.0f));
#pragma unroll
    for (int j = 0; j < 16; ++j) lds[tid + 272*j] = v[j];
    __syncthreads();
#pragma unroll
    for (int j = 0; j < 16; ++j) v[j] = lds[n1 + 16*j + 272*hi];
    __syncthreads();
    dft16<SIGN>(v);
#pragma unroll
    for (int j = 0; j < 16; ++j) lds[(j*16 + hi)*17 + n1] = v[j];
    __syncthreads();
#pragma unroll
    for (int j = 0; j < 16; ++j) v[j] = lds[tid*17 + j];
    twiddle_pow(v, sg * TWO_PI * (float)tid * (1.0f/4096.0f));
    dft16<SIGN>(v);
    __syncthreads();
}

#define COSJ_INIT { 1.0f, 0.980785280403230f, 0.923879532511287f, 0.831469612302545f, \
    0.707106781186548f, 0.555570233019602f, 0.382683432365090f, 0.195090322016128f, \
    0.0f, -0.195090322016128f, -0.382683432365090f, -0.555570233019602f, \
    -0.707106781186548f, -0.831469612302545f, -0.923879532511287f, -0.980785280403230f }
#define SINJ_INIT { 0.0f, 0.195090322016128f, 0.382683432365090f, 0.555570233019602f, \
    0.707106781186548f, 0.831469612302545f, 0.923879532511287f, 0.980785280403230f, \
    1.0f, 0.980785280403230f, 0.923879532511287f, 0.831469612302545f, \
    0.707106781186548f, 0.555570233019602f, 0.382683432365090f, 0.195090322016128f }

// ---------------------------------------------------------------------------
// Kernel A: rfft of each (b,c) row, ortho norm.
// ---------------------------------------------------------------------------
__global__ __launch_bounds__(256, 4) void k_rfft(const float* __restrict__ x,
                                                 float* __restrict__ fxr,
                                                 float* __restrict__ fxi)
{
    __shared__ float2 lds[4352];
    int bc = blockIdx.x, tid = threadIdx.x;
    const float2* xr = (const float2*)(x + (size_t)bc * LL);
    float2 v[16];
#pragma unroll
    for (int j = 0; j < 16; ++j) v[j] = xr[tid + 256*j];
    fft4096_regs<-1>(v, lds, tid);
#pragma unroll
    for (int j = 0; j < 16; ++j) lds[tid + 256*j] = v[j];
    __syncthreads();

    const float scale = 0.011048543456039806f; // 1/sqrt(8192)
    const float COSJ[16] = COSJ_INIT;
    const float SINJ[16] = SINJ_INIT;
    size_t row = (size_t)bc * FP;
    float sA, cA; __sincosf(3.14159265358979f * (float)tid * (1.0f/4096.0f), &sA, &cA);
#pragma unroll
    for (int j = 0; j < 16; ++j){
        int k = tid + 256*j;
        if (k == 0){
            float2 z0 = lds[0];
            fxr[row + 0]  = (z0.x + z0.y) * scale; fxi[row + 0]  = 0.0f;
            fxr[row + M4] = (z0.x - z0.y) * scale; fxi[row + M4] = 0.0f;
        } else {
            float2 zk = lds[k], zm = lds[(4096 - k) & 4095];
            float er = 0.5f*(zk.x + zm.x), ei = 0.5f*(zk.y - zm.y);
            float dr = 0.5f*(zk.x - zm.x), di = 0.5f*(zk.y + zm.y);
            float cp = cA*COSJ[j] - sA*SINJ[j];
            float sp = sA*COSJ[j] + cA*SINJ[j];
            fxr[row + k] = (er + cp*di - sp*dr) * scale;
            fxi[row + k] = (ei - cp*dr - sp*di) * scale;
        }
    }
}

// ---------------------------------------------------------------------------
// Prep: pack conv1 weights to bf16 in MFMA K-order.
// ---------------------------------------------------------------------------
__global__ __launch_bounds__(256) void k_pack(const float* __restrict__ wR1,
                                              const float* __restrict__ wI1,
                                              short* __restrict__ Wp)
{
    int idx = blockIdx.x * 256 + threadIdx.x;
    if (idx >= 2 * 128 * 192) return;
    int enc = idx / (128 * 192);
    int rem = idx - enc * (128 * 192);
    int h = rem / 192;
    int k = rem - h * 192;
    int s = k >> 5;
    int j = k & 31;
    int kap = s >> 1;
    int c = (s & 1) * 32 + j;
    const float* w = enc ? wI1 : wR1;
    Wp[idx] = f2bf(w[(h * 64 + c) * 3 + kap]);
}

// ---------------------------------------------------------------------------
// Kernel B1 (MFMA): conv1 + bias + SELU + partial sums + endpoints.
// 5 tiles per block, double-buffered swizzled LDS, vectorized staging.
// LDS layout: Xt[buf][tt][c], tt row = 64 shorts = 128 B, swizzle:
//   short_idx = (tt*64 + c) ^ ((tt&7)<<3)   -> conflict-free ds_read_b128.
// ---------------------------------------------------------------------------
struct Stage {
    float4 f[4];
    float hv;
};

__device__ __forceinline__ void stage_issue(const float* __restrict__ srow,
                                            const float* __restrict__ xb,
                                            int tid, int hcc, int hhal,
                                            int t0, Stage& S)
{
#pragma unroll
    for (int v = 0; v < 4; ++v)
        S.f[v] = *(const float4*)(srow + t0 + v * 4);
    if (tid < 128) {
        int ht  = hhal ? (t0 + 64) : (t0 - 1);
        int hts = ht < 0 ? 0 : ht;
        S.hv = xb[(size_t)hcc * FP + hts];
    }
}

__device__ __forceinline__ void stage_commit(const Stage& S, short* __restrict__ Xb,
                                             int tid, int sc, int siq, int hcc, int hhal,
                                             int t0)
{
    bool allv = (t0 + 64) <= FF;   // every bulk t (t0..t0+63) < FF
    const float* fp = (const float*)&S.f[0];
#pragma unroll
    for (int u = 0; u < 16; ++u) {
        int tloc = siq * 16 + u;
        float val = fp[u];
        if (!allv) val = (t0 + tloc) < FF ? val : 0.0f;
        int tt = tloc + 1;
        Xb[(tt * 64 + sc) ^ ((tt & 7) << 3)] = f2bf(val);
    }
    if (tid < 128) {
        int ht = hhal ? (t0 + 64) : (t0 - 1);
        float v = (ht >= 0 && ht < FF) ? S.hv : 0.0f;
        int tt = hhal ? 65 : 0;
        Xb[(tt * 64 + hcc) ^ ((tt & 7) << 3)] = f2bf(v);
    }
}

__global__ __launch_bounds__(256, 3) void k_conv_mfma(const float* __restrict__ fxr,
                                                      const float* __restrict__ fxi,
                                                      const short* __restrict__ Wp,
                                                      const float* __restrict__ bR1,
                                                      const float* __restrict__ bI1,
                                                      float* __restrict__ part,
                                                      float* __restrict__ e0,
                                                      float* __restrict__ e1)
{
    __shared__ short Xt[2][66 * 64];
    int chunk = blockIdx.x;
    int b     = blockIdx.y;
    int enc   = blockIdx.z;
    const float* src = enc ? fxi : fxr;
    const float* b1  = enc ? bI1 : bR1;
    int tid = threadIdx.x;
    const float* xb = src + (size_t)b * 64 * FP;

    // staging thread mapping: bulk (c, t-quarter), halo (c, side)
    int sc   = tid >> 2;
    int siq  = tid & 3;
    const float* srow = xb + (size_t)sc * FP + siq * 16;
    int hcc  = tid >> 1;
    int hhal = tid & 1;

    int w = tid >> 6;
    int lane = tid & 63;
    int n = lane & 15;
    int q = lane >> 4;
    int h0 = w * 32;

    // A-fragments (weights), resident for the whole block
    short8 afrag[2][6];
    const short* wbase = Wp + (size_t)enc * 128 * 192;
#pragma unroll
    for (int hb = 0; hb < 2; ++hb)
#pragma unroll
        for (int s = 0; s < 6; ++s)
            afrag[hb][s] = *(const short8*)(wbase + (h0 + hb * 16 + n) * 192 + s * 32 + q * 8);

    // bias, hoisted
    float b1v[2][4];
#pragma unroll
    for (int hb = 0; hb < 2; ++hb)
#pragma unroll
        for (int r = 0; r < 4; ++r)
            b1v[hb][r] = b1[h0 + hb * 16 + q * 4 + r];

    const float SELU_S = 1.0507009873554805f;
    const float SELU_A = 1.6732632423543772f;
    int ebase = (enc * 64 + b) * 128;
    int tbase = chunk * (TPB * 64);

    // prologue: stage tile 0 into buffer 0
    {
        Stage S0;
        stage_issue(srow, xb, tid, hcc, hhal, tbase, S0);
        stage_commit(S0, Xt[0], tid, sc, siq, hcc, hhal, tbase);
    }
    __syncthreads();

    float hsum[2][4] = {{0.f,0.f,0.f,0.f},{0.f,0.f,0.f,0.f}};

#pragma unroll
    for (int ti = 0; ti < TPB; ++ti) {
        int t0 = tbase + ti * 64;
        const short* Xc = Xt[ti & 1];

        // issue next tile's global loads early (latency hides under MFMA+SELU)
        Stage Sn;
        if (ti + 1 < TPB)
            stage_issue(srow, xb, tid, hcc, hhal, t0 + 64, Sn);

        floatx4 acc[2][4] = {};
#pragma unroll
        for (int s = 0; s < 6; ++s) {
            int kap = s >> 1;
            int cbase = (s & 1) * 32 + q * 8;
#pragma unroll
            for (int tb = 0; tb < 4; ++tb) {
                int row = tb * 16 + n + kap;
                short8 bfrag = *(const short8*)(Xc + ((row * 64 + cbase) ^ ((row & 7) << 3)));
                acc[0][tb] = __builtin_amdgcn_mfma_f32_16x16x32_bf16(afrag[0][s], bfrag, acc[0][tb], 0, 0, 0);
                acc[1][tb] = __builtin_amdgcn_mfma_f32_16x16x32_bf16(afrag[1][s], bfrag, acc[1][tb], 0, 0, 0);
            }
        }

        bool edge = (t0 == 0) || (t0 == 4096);
        bool allv = (t0 + 63) < FF;
#pragma unroll
        for (int hb = 0; hb < 2; ++hb) {
#pragma unroll
            for (int tb = 0; tb < 4; ++tb) {
                int t = t0 + tb * 16 + n;
                bool valid = t < FF;
#pragma unroll
                for (int r = 0; r < 4; ++r) {
                    float val = acc[hb][tb][r] + b1v[hb][r];
                    float y = SELU_S * (val > 0.0f ? val : SELU_A * (__expf(val) - 1.0f));
                    if (!allv) y = valid ? y : 0.0f;
                    hsum[hb][r] += y;
                    if (edge) {
                        int h = h0 + hb * 16 + q * 4 + r;
                        if (t == 0)      e0[ebase + h] = y;
                        if (t == FF - 1) e1[ebase + h] = y;
                    }
                }
            }
        }

        // write next tile into the other buffer (waits on its loads here)
        if (ti + 1 < TPB)
            stage_commit(Sn, Xt[(ti + 1) & 1], tid, sc, siq, hcc, hhal, t0 + 64);
        __syncthreads();
    }

    // one reduction + one coalesced partial write per block
#pragma unroll
    for (int off = 1; off < 16; off <<= 1)
#pragma unroll
        for (int hb = 0; hb < 2; ++hb)
#pragma unroll
            for (int r = 0; r < 4; ++r)
                hsum[hb][r] += __shfl_xor(hsum[hb][r], off, 64);

    if (n == 0) {
#pragma unroll
        for (int hb = 0; hb < 2; ++hb) {
            size_t idx = ((size_t)(chunk * 2 + enc) * 64 + b) * 128 + h0 + hb * 16 + q * 4;
            *(float4*)(part + idx) = make_float4(hsum[hb][0], hsum[hb][1], hsum[hb][2], hsum[hb][3]);
        }
    }
}

// ---------------------------------------------------------------------------
// Kernel B2: conv2 (mean via endpoint algebra) + bias + softmax
// ---------------------------------------------------------------------------
__global__ __launch_bounds__(128) void k_head(const float* __restrict__ part,
                                              const float* __restrict__ e0,
                                              const float* __restrict__ e1,
                                              const float* __restrict__ wR2,
                                              const float* __restrict__ bR2,
                                              const float* __restrict__ wI2,
                                              const float* __restrict__ bI2,
                                              float* __restrict__ Cw)
{
    __shared__ float red[3][128];
    int b   = blockIdx.x;
    int enc = blockIdx.y;
    const float* w2 = enc ? wI2 : wR2;
    const float* b2 = enc ? bI2 : bR2;
    int h = threadIdx.x;
    float T = 0.0f;
    for (int t = 0; t < NCH; ++t)
        T += part[((size_t)(t * 2 + enc) * 64 + b) * 128 + h];
    float e0v = e0[(enc * 64 + b) * 128 + h];
    float e1v = e1[(enc * 64 + b) * 128 + h];
#pragma unroll
    for (int nn = 0; nn < 3; ++nn) {
        const float* wp = w2 + (nn * 128 + h) * 3;
        red[nn][h] = wp[0] * (T - e1v) + wp[1] * T + wp[2] * (T - e0v);
    }
    __syncthreads();
    if (h == 0) {
        float lg[3];
        for (int nn = 0; nn < 3; ++nn) {
            float s = 0.0f;
            for (int qq = 0; qq < 128; ++qq) s += red[nn][qq];
            lg[nn] = b2[nn] + s / 4097.0f;
        }
        float mx = fmaxf(lg[0], fmaxf(lg[1], lg[2]));
        float ex0 = __expf(lg[0] - mx);
        float ex1 = __expf(lg[1] - mx);
        float ex2 = __expf(lg[2] - mx);
        float den = ex0 + ex1 + ex2;
        Cw[(enc * 64 + b) * 3 + 0] = ex0 / den;
        Cw[(enc * 64 + b) * 3 + 1] = ex1 / den;
        Cw[(enc * 64 + b) * 3 + 2] = ex2 / den;
    }
}

// ---------------------------------------------------------------------------
// Kernel C: P = fx*Kf -> inverse FFT (register radix-16^3) -> out row.
// ---------------------------------------------------------------------------
__global__ __launch_bounds__(256, 4) void k_irfft(const float* __restrict__ fxr,
                                                  const float* __restrict__ fxi,
                                                  const float* __restrict__ param,
                                                  const float* __restrict__ Cw,
                                                  float* __restrict__ out)
{
    __shared__ float2 lds[4352];
    int bc = blockIdx.x, b = bc >> 6, c = bc & 63, tid = threadIdx.x;
    float cr0 = Cw[b*3+0], cr1 = Cw[b*3+1], cr2 = Cw[b*3+2];
    float ci0 = Cw[192 + b*3+0], ci1 = Cw[192 + b*3+1], ci2 = Cw[192 + b*3+2];
    size_t row = (size_t)bc * FP;
    const float2* W0 = (const float2*)param + (size_t)(0*64 + c) * FF;
    const float2* W1 = (const float2*)param + (size_t)(1*64 + c) * FF;
    const float2* W2 = (const float2*)param + (size_t)(2*64 + c) * FF;

    for (int f = tid; f <= 4096; f += 256) {
        float2 w0 = W0[f], w1 = W1[f], w2 = W2[f];
        float kr = cr0*w0.x + cr1*w1.x + cr2*w2.x;
        float ki = ci0*w0.y + ci1*w1.y + ci2*w2.y;
        float fr = fxr[row + f], fi = fxi[row + f];
        lds[f] = make_float2(fr*kr - fi*ki, fr*ki + fi*kr);
    }
    __syncthreads();

    const float COSJ[16] = COSJ_INIT;
    const float SINJ[16] = SINJ_INIT;
    float2 v[16];
    float sA, cA; __sincosf(3.14159265358979f * (float)tid * (1.0f/4096.0f), &sA, &cA);
#pragma unroll
    for (int j = 0; j < 16; ++j) {
        int m = tid + 256*j;
        if (m == 0) {
            float p0 = lds[0].x, pn = lds[4096].x;
            v[j] = make_float2(0.5f*(p0 + pn), 0.5f*(p0 - pn));
        } else {
            float2 p = lds[m], qq = lds[4096 - m];
            float er = 0.5f*(p.x + qq.x), ei = 0.5f*(p.y - qq.y);
            float dr = 0.5f*(p.x - qq.x), di = 0.5f*(p.y + qq.y);
            float cp = cA*COSJ[j] - sA*SINJ[j];
            float sp = sA*COSJ[j] + cA*SINJ[j];
            float zor = dr*cp - di*sp;
            float zoi = dr*sp + di*cp;
            v[j] = make_float2(er - zoi, ei + zor);
        }
    }
    __syncthreads();
    fft4096_regs<1>(v, lds, tid);

    const float S = 0.02209708691207961f;  // sqrt(8192)/4096
    float2* orow = (float2*)(out + (size_t)bc * LL);
#pragma unroll
    for (int j = 0; j < 16; ++j) {
        float2 z = v[j];
        orow[tid + 256*j] = make_float2(S*z.x, S*z.y);
    }
}

// ---------------------------------------------------------------------------
extern "C" void kernel_launch(void* const* d_in, const int* in_sizes, int n_in,
                              void* d_out, int out_size, void* d_ws, size_t ws_size,
                              hipStream_t stream)
{
    (void)in_sizes; (void)n_in; (void)out_size; (void)ws_size;
    const float* x   = (const float*)d_in[0];
    const float* prm = (const float*)d_in[1];
    const float* wR1 = (const float*)d_in[2];
    const float* bR1 = (const float*)d_in[3];
    const float* wR2 = (const float*)d_in[4];
    const float* bR2 = (const float*)d_in[5];
    const float* wI1 = (const float*)d_in[6];
    const float* bI1 = (const float*)d_in[7];
    const float* wI2 = (const float*)d_in[8];
    const float* bI2 = (const float*)d_in[9];
    float* out = (float*)d_out;
    float* ws  = (float*)d_ws;

    size_t o = 0;
    float* fxr  = ws + o; o += (size_t)BB * CCH * FP;
    float* fxi  = ws + o; o += (size_t)BB * CCH * FP;
    float* part = ws + o; o += (size_t)NCH * 2 * 64 * 128;
    float* e0   = ws + o; o += 2 * 64 * 128;
    float* e1   = ws + o; o += 2 * 64 * 128;
    float* Cw   = ws + o; o += 2 * 64 * 4;
    short* Wp   = (short*)(ws + o); o += (size_t)2 * 128 * 192 / 2;

    k_rfft<<<dim3(4096), dim3(256), 0, stream>>>(x, fxr, fxi);
    k_pack<<<dim3((2 * 128 * 192 + 255) / 256), dim3(256), 0, stream>>>(wR1, wI1, Wp);
    k_conv_mfma<<<dim3(NCH, 64, 2), dim3(256), 0, stream>>>(fxr, fxi, Wp, bR1, bI1,
                                                            part, e0, e1);
    k_head<<<dim3(64, 2), dim3(128), 0, stream>>>(part, e0, e1, wR2, bR2, wI2, bI2, Cw);
    k_irfft<<<dim3(4096), dim3(256), 0, stream>>>(fxr, fxi, prm, Cw, out);
}

// Round 2
// 393.545 us; speedup vs baseline: 1.2431x; 1.2431x over previous
//
#include <hip/hip_runtime.h>
#include <math.h>

// Problem constants
#define BB 64
#define CCH 64
#define LL 8192
#define FF 4097
#define FP 4104   // padded row stride for spectra
#define M4 4096
#define NT 65     // 64-wide t tiles over F=4097

typedef __attribute__((ext_vector_type(8))) short short8;
typedef __attribute__((ext_vector_type(4))) float floatx4;

__device__ __forceinline__ short f2bf(float v) {
    union { float f; unsigned u; } cv; cv.f = v;
    unsigned r = (cv.u + 0x7fffu + ((cv.u >> 16) & 1u)) >> 16;
    return (short)r;
}

// ---------------- complex helpers ----------------
__device__ __forceinline__ float2 cadd(float2 a, float2 b){ return make_float2(a.x+b.x, a.y+b.y); }
__device__ __forceinline__ float2 csub(float2 a, float2 b){ return make_float2(a.x-b.x, a.y-b.y); }
__device__ __forceinline__ float2 cmul(float2 a, float2 b){ return make_float2(a.x*b.x-a.y*b.y, a.x*b.y+a.y*b.x); }
template<int SIGN> __device__ __forceinline__ float2 roti(float2 a){
    return (SIGN < 0) ? make_float2(a.y, -a.x) : make_float2(-a.y, a.x);
}
template<int SIGN>
__device__ __forceinline__ void dft4(float2& a, float2& b, float2& c, float2& d){
    float2 t0 = cadd(a,c), t1 = csub(a,c), t2 = cadd(b,d), t3 = roti<SIGN>(csub(b,d));
    a = cadd(t0,t2); b = cadd(t1,t3); c = csub(t0,t2); d = csub(t1,t3);
}

// DFT-16, natural order in and out, fully unrolled, constant twiddles.
template<int SIGN>
__device__ __forceinline__ void dft16(float2 v[16]){
    const float C1 = 0.9238795325112867f, S1 = 0.3826834323650898f, R2 = 0.7071067811865476f;
    const float sg = (SIGN < 0) ? -1.0f : 1.0f;
#pragma unroll
    for (int n1 = 0; n1 < 4; ++n1) dft4<SIGN>(v[n1], v[n1+4], v[n1+8], v[n1+12]);
    const float2 W1 = make_float2( C1, sg*S1);
    const float2 W2 = make_float2( R2, sg*R2);
    const float2 W3 = make_float2( S1, sg*C1);
    const float2 W6 = make_float2(-R2, sg*R2);
    const float2 W9 = make_float2(-C1, -sg*S1);
    v[5]  = cmul(v[5],  W1); v[6]  = cmul(v[6],  W2); v[7]  = cmul(v[7],  W3);
    v[9]  = cmul(v[9],  W2); v[10] = roti<SIGN>(v[10]); v[11] = cmul(v[11], W6);
    v[13] = cmul(v[13], W3); v[14] = cmul(v[14], W6); v[15] = cmul(v[15], W9);
#pragma unroll
    for (int k2 = 0; k2 < 4; ++k2) dft4<SIGN>(v[4*k2+0], v[4*k2+1], v[4*k2+2], v[4*k2+3]);
    float2 t[16];
#pragma unroll
    for (int k = 0; k < 16; ++k) t[k] = v[4*(k & 3) + (k >> 2)];
#pragma unroll
    for (int k = 0; k < 16; ++k) v[k] = t[k];
}

__device__ __forceinline__ void twiddle_pow(float2 v[16], float ang){
    float s, c; __sincosf(ang, &s, &c);
    float2 w = make_float2(c, s), t = w;
    v[1] = cmul(v[1], t);
#pragma unroll
    for (int j = 2; j < 16; ++j){ t = cmul(t, w); v[j] = cmul(v[j], t); }
}

template<int SIGN>
__device__ __forceinline__ void fft4096_regs(float2 v[16], float2* lds, int tid){
    const float TWO_PI = 6.283185307179586f;
    const float sg = (SIGN < 0) ? -1.0f : 1.0f;
    int n1 = tid & 15, hi = tid >> 4;
    dft16<SIGN>(v);
    twiddle_pow(v, sg * TWO_PI * (float)hi * (1.0f/256.0f));
#pragma unroll
    for (int j = 0; j < 16; ++j) lds[tid + 272*j] = v[j];
    __syncthreads();
#pragma unroll
    for (int j = 0; j < 16; ++j) v[j] = lds[n1 + 16*j + 272*hi];
    __syncthreads();
    dft16<SIGN>(v);
#pragma unroll
    for (int j = 0; j < 16; ++j) lds[(j*16 + hi)*17 + n1] = v[j];
    __syncthreads();
#pragma unroll
    for (int j = 0; j < 16; ++j) v[j] = lds[tid*17 + j];
    twiddle_pow(v, sg * TWO_PI * (float)tid * (1.0f/4096.0f));
    dft16<SIGN>(v);
    __syncthreads();
}

#define COSJ_INIT { 1.0f, 0.980785280403230f, 0.923879532511287f, 0.831469612302545f, \
    0.707106781186548f, 0.555570233019602f, 0.382683432365090f, 0.195090322016128f, \
    0.0f, -0.195090322016128f, -0.382683432365090f, -0.555570233019602f, \
    -0.707106781186548f, -0.831469612302545f, -0.923879532511287f, -0.980785280403230f }
#define SINJ_INIT { 0.0f, 0.195090322016128f, 0.382683432365090f, 0.555570233019602f, \
    0.707106781186548f, 0.831469612302545f, 0.923879532511287f, 0.980785280403230f, \
    1.0f, 0.980785280403230f, 0.923879532511287f, 0.831469612302545f, \
    0.707106781186548f, 0.555570233019602f, 0.382683432365090f, 0.195090322016128f }

// ---------------------------------------------------------------------------
// Kernel A: rfft of each (b,c) row, ortho norm.
// ---------------------------------------------------------------------------
__global__ __launch_bounds__(256, 4) void k_rfft(const float* __restrict__ x,
                                                 float* __restrict__ fxr,
                                                 float* __restrict__ fxi)
{
    __shared__ float2 lds[4352];
    int bc = blockIdx.x, tid = threadIdx.x;
    const float2* xr = (const float2*)(x + (size_t)bc * LL);
    float2 v[16];
#pragma unroll
    for (int j = 0; j < 16; ++j) v[j] = xr[tid + 256*j];
    fft4096_regs<-1>(v, lds, tid);
#pragma unroll
    for (int j = 0; j < 16; ++j) lds[tid + 256*j] = v[j];
    __syncthreads();

    const float scale = 0.011048543456039806f; // 1/sqrt(8192)
    const float COSJ[16] = COSJ_INIT;
    const float SINJ[16] = SINJ_INIT;
    size_t row = (size_t)bc * FP;
    float sA, cA; __sincosf(3.14159265358979f * (float)tid * (1.0f/4096.0f), &sA, &cA);
#pragma unroll
    for (int j = 0; j < 16; ++j){
        int k = tid + 256*j;
        if (k == 0){
            float2 z0 = lds[0];
            fxr[row + 0]  = (z0.x + z0.y) * scale; fxi[row + 0]  = 0.0f;
            fxr[row + M4] = (z0.x - z0.y) * scale; fxi[row + M4] = 0.0f;
        } else {
            float2 zk = lds[k], zm = lds[(4096 - k) & 4095];
            float er = 0.5f*(zk.x + zm.x), ei = 0.5f*(zk.y - zm.y);
            float dr = 0.5f*(zk.x - zm.x), di = 0.5f*(zk.y + zm.y);
            float cp = cA*COSJ[j] - sA*SINJ[j];
            float sp = sA*COSJ[j] + cA*SINJ[j];
            fxr[row + k] = (er + cp*di - sp*dr) * scale;
            fxi[row + k] = (ei - cp*dr - sp*di) * scale;
        }
    }
}

// ---------------------------------------------------------------------------
// Prep: pack conv1 weights to bf16 in MFMA K-order.
// ---------------------------------------------------------------------------
__global__ __launch_bounds__(256) void k_pack(const float* __restrict__ wR1,
                                              const float* __restrict__ wI1,
                                              short* __restrict__ Wp)
{
    int idx = blockIdx.x * 256 + threadIdx.x;
    if (idx >= 2 * 128 * 192) return;
    int enc = idx / (128 * 192);
    int rem = idx - enc * (128 * 192);
    int h = rem / 192;
    int k = rem - h * 192;
    int s = k >> 5;
    int j = k & 31;
    int kap = s >> 1;
    int c = (s & 1) * 32 + j;
    const float* w = enc ? wI1 : wR1;
    Wp[idx] = f2bf(w[(h * 64 + c) * 3 + kap]);
}

// ---------------------------------------------------------------------------
// Kernel B1 (MFMA): conv1 + bias + SELU + partial sums + endpoints.
// Single tile per block (occupancy hides latency). Swizzled LDS [66][64]:
//   short_idx = (tt*64 + c) ^ ((tt&7)<<3)
//   - staging: wave w = t-quarter, lane = c -> float4 global loads, per-u LDS
//     row writes are 64 consecutive shorts => conflict-free
//   - MFMA ds_read_b128: 8 lanes per 4-bank group => conflict-free
// ---------------------------------------------------------------------------
__global__ __launch_bounds__(256, 4) void k_conv_mfma(const float* __restrict__ fxr,
                                                      const float* __restrict__ fxi,
                                                      const short* __restrict__ Wp,
                                                      const float* __restrict__ bR1,
                                                      const float* __restrict__ bI1,
                                                      float* __restrict__ part,
                                                      float* __restrict__ e0,
                                                      float* __restrict__ e1)
{
    __shared__ short Xt[66 * 64];
    int tile = blockIdx.x;
    int b    = blockIdx.y;
    int enc  = blockIdx.z;
    const float* src = enc ? fxi : fxr;
    const float* b1  = enc ? bI1 : bR1;
    int tid = threadIdx.x;
    int t0 = tile * 64;
    const float* xb = src + (size_t)b * 64 * FP;

    // ---- staging ----
    int sw  = tid >> 6;   // wave id = t-quarter
    int scc = tid & 63;   // channel
    {
        const float* srow = xb + (size_t)scc * FP + t0 + sw * 16;
        float4 f0 = *(const float4*)(srow + 0);
        float4 f1 = *(const float4*)(srow + 4);
        float4 f2 = *(const float4*)(srow + 8);
        float4 f3 = *(const float4*)(srow + 12);
        float vals[16] = { f0.x, f0.y, f0.z, f0.w,  f1.x, f1.y, f1.z, f1.w,
                           f2.x, f2.y, f2.z, f2.w,  f3.x, f3.y, f3.z, f3.w };
        bool allv = (t0 + 64) <= FF;
#pragma unroll
        for (int u = 0; u < 16; ++u) {
            float val = vals[u];
            if (!allv) val = (t0 + sw * 16 + u) < FF ? val : 0.0f;
            int tt = sw * 16 + u + 1;
            Xt[(tt * 64 + scc) ^ ((tt & 7) << 3)] = f2bf(val);
        }
        if (tid < 128) {                  // waves 0,1: halo columns (uniform branch)
            int hhal = tid >> 6;          // 0: t0-1 row, 1: t0+64 row
            int ht = hhal ? (t0 + 64) : (t0 - 1);
            int hts = ht < 0 ? 0 : (ht >= FF ? FF - 1 : ht);
            float v = xb[(size_t)scc * FP + hts];
            if (ht < 0 || ht >= FF) v = 0.0f;
            int tt = hhal ? 65 : 0;
            Xt[(tt * 64 + scc) ^ ((tt & 7) << 3)] = f2bf(v);
        }
    }
    __syncthreads();

    int w = tid >> 6;
    int lane = tid & 63;
    int n = lane & 15;
    int q = lane >> 4;
    int h0 = w * 32;

    short8 afrag[2][6];
    const short* wbase = Wp + (size_t)enc * 128 * 192;
#pragma unroll
    for (int hb = 0; hb < 2; ++hb)
#pragma unroll
        for (int s = 0; s < 6; ++s)
            afrag[hb][s] = *(const short8*)(wbase + (h0 + hb * 16 + n) * 192 + s * 32 + q * 8);

    floatx4 acc[2][4] = {};
#pragma unroll
    for (int s = 0; s < 6; ++s) {
        int kap = s >> 1;
        int cbase = (s & 1) * 32 + q * 8;
#pragma unroll
        for (int tb = 0; tb < 4; ++tb) {
            int row = tb * 16 + n + kap;
            short8 bfrag = *(const short8*)(Xt + ((row * 64 + cbase) ^ ((row & 7) << 3)));
            acc[0][tb] = __builtin_amdgcn_mfma_f32_16x16x32_bf16(afrag[0][s], bfrag, acc[0][tb], 0, 0, 0);
            acc[1][tb] = __builtin_amdgcn_mfma_f32_16x16x32_bf16(afrag[1][s], bfrag, acc[1][tb], 0, 0, 0);
        }
    }

    const float SELU_S = 1.0507009873554805f;
    const float SELU_A = 1.6732632423543772f;
    int ebase = (enc * 64 + b) * 128;
    bool edge = (t0 == 0) || (t0 == 4096);
    bool allv = (t0 + 63) < FF;
    float hsum[2][4] = {{0.f,0.f,0.f,0.f},{0.f,0.f,0.f,0.f}};
#pragma unroll
    for (int hb = 0; hb < 2; ++hb) {
#pragma unroll
        for (int tb = 0; tb < 4; ++tb) {
            int t = t0 + tb * 16 + n;
            bool valid = t < FF;
#pragma unroll
            for (int r = 0; r < 4; ++r) {
                float bv = b1[h0 + hb * 16 + q * 4 + r];
                float val = acc[hb][tb][r] + bv;
                float y = SELU_S * (val > 0.0f ? val : SELU_A * (__expf(val) - 1.0f));
                if (!allv) y = valid ? y : 0.0f;
                hsum[hb][r] += y;
                if (edge) {
                    int h = h0 + hb * 16 + q * 4 + r;
                    if (t == 0)      e0[ebase + h] = y;
                    if (t == FF - 1) e1[ebase + h] = y;
                }
            }
        }
    }

#pragma unroll
    for (int off = 1; off < 16; off <<= 1)
#pragma unroll
        for (int hb = 0; hb < 2; ++hb)
#pragma unroll
            for (int r = 0; r < 4; ++r)
                hsum[hb][r] += __shfl_xor(hsum[hb][r], off, 64);

    if (n == 0) {
#pragma unroll
        for (int hb = 0; hb < 2; ++hb) {
            size_t idx = ((size_t)(tile * 2 + enc) * 64 + b) * 128 + h0 + hb * 16 + q * 4;
            *(float4*)(part + idx) = make_float4(hsum[hb][0], hsum[hb][1], hsum[hb][2], hsum[hb][3]);
        }
    }
}

// ---------------------------------------------------------------------------
// Kernel B2: conv2 (mean via endpoint algebra) + bias + softmax
// ---------------------------------------------------------------------------
__global__ __launch_bounds__(128) void k_head(const float* __restrict__ part,
                                              const float* __restrict__ e0,
                                              const float* __restrict__ e1,
                                              const float* __restrict__ wR2,
                                              const float* __restrict__ bR2,
                                              const float* __restrict__ wI2,
                                              const float* __restrict__ bI2,
                                              float* __restrict__ Cw)
{
    __shared__ float red[3][128];
    int b   = blockIdx.x;
    int enc = blockIdx.y;
    const float* w2 = enc ? wI2 : wR2;
    const float* b2 = enc ? bI2 : bR2;
    int h = threadIdx.x;
    float T = 0.0f;
    for (int t = 0; t < NT; ++t)
        T += part[((size_t)(t * 2 + enc) * 64 + b) * 128 + h];
    float e0v = e0[(enc * 64 + b) * 128 + h];
    float e1v = e1[(enc * 64 + b) * 128 + h];
#pragma unroll
    for (int nn = 0; nn < 3; ++nn) {
        const float* wp = w2 + (nn * 128 + h) * 3;
        red[nn][h] = wp[0] * (T - e1v) + wp[1] * T + wp[2] * (T - e0v);
    }
    __syncthreads();
    if (h == 0) {
        float lg[3];
        for (int nn = 0; nn < 3; ++nn) {
            float s = 0.0f;
            for (int qq = 0; qq < 128; ++qq) s += red[nn][qq];
            lg[nn] = b2[nn] + s / 4097.0f;
        }
        float mx = fmaxf(lg[0], fmaxf(lg[1], lg[2]));
        float ex0 = __expf(lg[0] - mx);
        float ex1 = __expf(lg[1] - mx);
        float ex2 = __expf(lg[2] - mx);
        float den = ex0 + ex1 + ex2;
        Cw[(enc * 64 + b) * 3 + 0] = ex0 / den;
        Cw[(enc * 64 + b) * 3 + 1] = ex1 / den;
        Cw[(enc * 64 + b) * 3 + 2] = ex2 / den;
    }
}

// ---------------------------------------------------------------------------
// Kernel C: P = fx*Kf -> inverse FFT (register radix-16^3) -> out row.
// ---------------------------------------------------------------------------
__global__ __launch_bounds__(256, 4) void k_irfft(const float* __restrict__ fxr,
                                                  const float* __restrict__ fxi,
                                                  const float* __restrict__ param,
                                                  const float* __restrict__ Cw,
                                                  float* __restrict__ out)
{
    __shared__ float2 lds[4352];
    int bc = blockIdx.x, b = bc >> 6, c = bc & 63, tid = threadIdx.x;
    float cr0 = Cw[b*3+0], cr1 = Cw[b*3+1], cr2 = Cw[b*3+2];
    float ci0 = Cw[192 + b*3+0], ci1 = Cw[192 + b*3+1], ci2 = Cw[192 + b*3+2];
    size_t row = (size_t)bc * FP;
    const float2* W0 = (const float2*)param + (size_t)(0*64 + c) * FF;
    const float2* W1 = (const float2*)param + (size_t)(1*64 + c) * FF;
    const float2* W2 = (const float2*)param + (size_t)(2*64 + c) * FF;

    for (int f = tid; f <= 4096; f += 256) {
        float2 w0 = W0[f], w1 = W1[f], w2 = W2[f];
        float kr = cr0*w0.x + cr1*w1.x + cr2*w2.x;
        float ki = ci0*w0.y + ci1*w1.y + ci2*w2.y;
        float fr = fxr[row + f], fi = fxi[row + f];
        lds[f] = make_float2(fr*kr - fi*ki, fr*ki + fi*kr);
    }
    __syncthreads();

    const float COSJ[16] = COSJ_INIT;
    const float SINJ[16] = SINJ_INIT;
    float2 v[16];
    float sA, cA; __sincosf(3.14159265358979f * (float)tid * (1.0f/4096.0f), &sA, &cA);
#pragma unroll
    for (int j = 0; j < 16; ++j) {
        int m = tid + 256*j;
        if (m == 0) {
            float p0 = lds[0].x, pn = lds[4096].x;
            v[j] = make_float2(0.5f*(p0 + pn), 0.5f*(p0 - pn));
        } else {
            float2 p = lds[m], qq = lds[4096 - m];
            float er = 0.5f*(p.x + qq.x), ei = 0.5f*(p.y - qq.y);
            float dr = 0.5f*(p.x - qq.x), di = 0.5f*(p.y + qq.y);
            float cp = cA*COSJ[j] - sA*SINJ[j];
            float sp = sA*COSJ[j] + cA*SINJ[j];
            float zor = dr*cp - di*sp;
            float zoi = dr*sp + di*cp;
            v[j] = make_float2(er - zoi, ei + zor);
        }
    }
    __syncthreads();
    fft4096_regs<1>(v, lds, tid);

    const float S = 0.02209708691207961f;  // sqrt(8192)/4096
    float2* orow = (float2*)(out + (size_t)bc * LL);
#pragma unroll
    for (int j = 0; j < 16; ++j) {
        float2 z = v[j];
        orow[tid + 256*j] = make_float2(S*z.x, S*z.y);
    }
}

// ---------------------------------------------------------------------------
extern "C" void kernel_launch(void* const* d_in, const int* in_sizes, int n_in,
                              void* d_out, int out_size, void* d_ws, size_t ws_size,
                              hipStream_t stream)
{
    (void)in_sizes; (void)n_in; (void)out_size; (void)ws_size;
    const float* x   = (const float*)d_in[0];
    const float* prm = (const float*)d_in[1];
    const float* wR1 = (const float*)d_in[2];
    const float* bR1 = (const float*)d_in[3];
    const float* wR2 = (const float*)d_in[4];
    const float* bR2 = (const float*)d_in[5];
    const float* wI1 = (const float*)d_in[6];
    const float* bI1 = (const float*)d_in[7];
    const float* wI2 = (const float*)d_in[8];
    const float* bI2 = (const float*)d_in[9];
    float* out = (float*)d_out;
    float* ws  = (float*)d_ws;

    size_t o = 0;
    float* fxr  = ws + o; o += (size_t)BB * CCH * FP;
    float* fxi  = ws + o; o += (size_t)BB * CCH * FP;
    float* part = ws + o; o += (size_t)NT * 2 * 64 * 128;
    float* e0   = ws + o; o += 2 * 64 * 128;
    float* e1   = ws + o; o += 2 * 64 * 128;
    float* Cw   = ws + o; o += 2 * 64 * 4;
    short* Wp   = (short*)(ws + o); o += (size_t)2 * 128 * 192 / 2;

    k_rfft<<<dim3(4096), dim3(256), 0, stream>>>(x, fxr, fxi);
    k_pack<<<dim3((2 * 128 * 192 + 255) / 256), dim3(256), 0, stream>>>(wR1, wI1, Wp);
    k_conv_mfma<<<dim3(NT, 64, 2), dim3(256), 0, stream>>>(fxr, fxi, Wp, bR1, bI1,
                                                           part, e0, e1);
    k_head<<<dim3(64, 2), dim3(128), 0, stream>>>(part, e0, e1, wR2, bR2, wI2, bI2, Cw);
    k_irfft<<<dim3(4096), dim3(256), 0, stream>>>(fxr, fxi, prm, Cw, out);
}

// Round 3
// 380.896 us; speedup vs baseline: 1.2844x; 1.0332x over previous
//
#include <hip/hip_runtime.h>
#include <math.h>

// Problem constants
#define BB 64
#define CCH 64
#define LL 8192
#define FF 4097
#define FP 4104   // padded row stride for spectra
#define M4 4096
#define NT 65     // 64-wide t tiles over F=4097

typedef __attribute__((ext_vector_type(8))) short short8;
typedef __attribute__((ext_vector_type(4))) float floatx4;

__device__ __forceinline__ short f2bf(float v) {
    union { float f; unsigned u; } cv; cv.f = v;
    unsigned r = (cv.u + 0x7fffu + ((cv.u >> 16) & 1u)) >> 16;
    return (short)r;
}

// ---------------- complex helpers ----------------
__device__ __forceinline__ float2 cadd(float2 a, float2 b){ return make_float2(a.x+b.x, a.y+b.y); }
__device__ __forceinline__ float2 csub(float2 a, float2 b){ return make_float2(a.x-b.x, a.y-b.y); }
__device__ __forceinline__ float2 cmul(float2 a, float2 b){ return make_float2(a.x*b.x-a.y*b.y, a.x*b.y+a.y*b.x); }
template<int SIGN> __device__ __forceinline__ float2 roti(float2 a){
    return (SIGN < 0) ? make_float2(a.y, -a.x) : make_float2(-a.y, a.x);
}
template<int SIGN>
__device__ __forceinline__ void dft4(float2& a, float2& b, float2& c, float2& d){
    float2 t0 = cadd(a,c), t1 = csub(a,c), t2 = cadd(b,d), t3 = roti<SIGN>(csub(b,d));
    a = cadd(t0,t2); b = cadd(t1,t3); c = csub(t0,t2); d = csub(t1,t3);
}

// DFT-16, natural order in and out, fully unrolled, constant twiddles.
template<int SIGN>
__device__ __forceinline__ void dft16(float2 v[16]){
    const float C1 = 0.9238795325112867f, S1 = 0.3826834323650898f, R2 = 0.7071067811865476f;
    const float sg = (SIGN < 0) ? -1.0f : 1.0f;
#pragma unroll
    for (int n1 = 0; n1 < 4; ++n1) dft4<SIGN>(v[n1], v[n1+4], v[n1+8], v[n1+12]);
    const float2 W1 = make_float2( C1, sg*S1);
    const float2 W2 = make_float2( R2, sg*R2);
    const float2 W3 = make_float2( S1, sg*C1);
    const float2 W6 = make_float2(-R2, sg*R2);
    const float2 W9 = make_float2(-C1, -sg*S1);
    v[5]  = cmul(v[5],  W1); v[6]  = cmul(v[6],  W2); v[7]  = cmul(v[7],  W3);
    v[9]  = cmul(v[9],  W2); v[10] = roti<SIGN>(v[10]); v[11] = cmul(v[11], W6);
    v[13] = cmul(v[13], W3); v[14] = cmul(v[14], W6); v[15] = cmul(v[15], W9);
#pragma unroll
    for (int k2 = 0; k2 < 4; ++k2) dft4<SIGN>(v[4*k2+0], v[4*k2+1], v[4*k2+2], v[4*k2+3]);
    float2 t[16];
#pragma unroll
    for (int k = 0; k < 16; ++k) t[k] = v[4*(k & 3) + (k >> 2)];
#pragma unroll
    for (int k = 0; k < 16; ++k) v[k] = t[k];
}

__device__ __forceinline__ void twiddle_pow(float2 v[16], float ang){
    float s, c; __sincosf(ang, &s, &c);
    float2 w = make_float2(c, s), t = w;
    v[1] = cmul(v[1], t);
#pragma unroll
    for (int j = 2; j < 16; ++j){ t = cmul(t, w); v[j] = cmul(v[j], t); }
}

template<int SIGN>
__device__ __forceinline__ void fft4096_regs(float2 v[16], float2* lds, int tid){
    const float TWO_PI = 6.283185307179586f;
    const float sg = (SIGN < 0) ? -1.0f : 1.0f;
    int n1 = tid & 15, hi = tid >> 4;
    dft16<SIGN>(v);
    twiddle_pow(v, sg * TWO_PI * (float)hi * (1.0f/256.0f));
#pragma unroll
    for (int j = 0; j < 16; ++j) lds[tid + 272*j] = v[j];
    __syncthreads();
#pragma unroll
    for (int j = 0; j < 16; ++j) v[j] = lds[n1 + 16*j + 272*hi];
    __syncthreads();
    dft16<SIGN>(v);
#pragma unroll
    for (int j = 0; j < 16; ++j) lds[(j*16 + hi)*17 + n1] = v[j];
    __syncthreads();
#pragma unroll
    for (int j = 0; j < 16; ++j) v[j] = lds[tid*17 + j];
    twiddle_pow(v, sg * TWO_PI * (float)tid * (1.0f/4096.0f));
    dft16<SIGN>(v);
    __syncthreads();
}

#define COSJ_INIT { 1.0f, 0.980785280403230f, 0.923879532511287f, 0.831469612302545f, \
    0.707106781186548f, 0.555570233019602f, 0.382683432365090f, 0.195090322016128f, \
    0.0f, -0.195090322016128f, -0.382683432365090f, -0.555570233019602f, \
    -0.707106781186548f, -0.831469612302545f, -0.923879532511287f, -0.980785280403230f }
#define SINJ_INIT { 0.0f, 0.195090322016128f, 0.382683432365090f, 0.555570233019602f, \
    0.707106781186548f, 0.831469612302545f, 0.923879532511287f, 0.980785280403230f, \
    1.0f, 0.980785280403230f, 0.923879532511287f, 0.831469612302545f, \
    0.707106781186548f, 0.555570233019602f, 0.382683432365090f, 0.195090322016128f }

// ---------------------------------------------------------------------------
// Kernel A: rfft of each (b,c) row, ortho norm.
// ---------------------------------------------------------------------------
__global__ __launch_bounds__(256, 4) void k_rfft(const float* __restrict__ x,
                                                 float* __restrict__ fxr,
                                                 float* __restrict__ fxi)
{
    __shared__ float2 lds[4352];
    int bc = blockIdx.x, tid = threadIdx.x;
    const float2* xr = (const float2*)(x + (size_t)bc * LL);
    float2 v[16];
#pragma unroll
    for (int j = 0; j < 16; ++j) v[j] = xr[tid + 256*j];
    fft4096_regs<-1>(v, lds, tid);
#pragma unroll
    for (int j = 0; j < 16; ++j) lds[tid + 256*j] = v[j];
    __syncthreads();

    const float scale = 0.011048543456039806f; // 1/sqrt(8192)
    const float COSJ[16] = COSJ_INIT;
    const float SINJ[16] = SINJ_INIT;
    size_t row = (size_t)bc * FP;
    float sA, cA; __sincosf(3.14159265358979f * (float)tid * (1.0f/4096.0f), &sA, &cA);
#pragma unroll
    for (int j = 0; j < 16; ++j){
        int k = tid + 256*j;
        if (k == 0){
            float2 z0 = lds[0];
            fxr[row + 0]  = (z0.x + z0.y) * scale; fxi[row + 0]  = 0.0f;
            fxr[row + M4] = (z0.x - z0.y) * scale; fxi[row + M4] = 0.0f;
        } else {
            float2 zk = lds[k], zm = lds[(4096 - k) & 4095];
            float er = 0.5f*(zk.x + zm.x), ei = 0.5f*(zk.y - zm.y);
            float dr = 0.5f*(zk.x - zm.x), di = 0.5f*(zk.y + zm.y);
            float cp = cA*COSJ[j] - sA*SINJ[j];
            float sp = sA*COSJ[j] + cA*SINJ[j];
            fxr[row + k] = (er + cp*di - sp*dr) * scale;
            fxi[row + k] = (ei - cp*dr - sp*di) * scale;
        }
    }
}

// ---------------------------------------------------------------------------
// Prep: pack conv1 weights to bf16 in MFMA K-order.
// ---------------------------------------------------------------------------
__global__ __launch_bounds__(256) void k_pack(const float* __restrict__ wR1,
                                              const float* __restrict__ wI1,
                                              short* __restrict__ Wp)
{
    int idx = blockIdx.x * 256 + threadIdx.x;
    if (idx >= 2 * 128 * 192) return;
    int enc = idx / (128 * 192);
    int rem = idx - enc * (128 * 192);
    int h = rem / 192;
    int k = rem - h * 192;
    int s = k >> 5;
    int j = k & 31;
    int kap = s >> 1;
    int c = (s & 1) * 32 + j;
    const float* w = enc ? wI1 : wR1;
    Wp[idx] = f2bf(w[(h * 64 + c) * 3 + kap]);
}

// ---------------------------------------------------------------------------
// Kernel B1 (MFMA): conv1 + bias + SELU + partial sums + endpoints.
// Round-3 changes:
//  - __launch_bounds__(256,5): VGPR cap ~102 so the 48-VGPR afrag set can
//    stay RESIDENT (round-2's 40-VGPR build re-loaded weights inside the
//    MFMA loop -> L2-latency-bound MFMA phase).
//  - afrag + bias loads hoisted to kernel top: their L2 latency hides under
//    the HBM staging wait. Keep-alive asm discourages sinking.
//  - acc initialized with bias via MFMA C-in (epilogue add removed).
// ---------------------------------------------------------------------------
__global__ __launch_bounds__(256, 5) void k_conv_mfma(const float* __restrict__ fxr,
                                                      const float* __restrict__ fxi,
                                                      const short* __restrict__ Wp,
                                                      const float* __restrict__ bR1,
                                                      const float* __restrict__ bI1,
                                                      float* __restrict__ part,
                                                      float* __restrict__ e0,
                                                      float* __restrict__ e1)
{
    __shared__ short Xt[66 * 64];
    int tile = blockIdx.x;
    int b    = blockIdx.y;
    int enc  = blockIdx.z;
    const float* src = enc ? fxi : fxr;
    const float* b1  = enc ? bI1 : bR1;
    int tid = threadIdx.x;
    int t0 = tile * 64;
    const float* xb = src + (size_t)b * 64 * FP;

    int w = tid >> 6;
    int lane = tid & 63;
    int n = lane & 15;
    int q = lane >> 4;
    int h0 = w * 32;

    // ---- weight fragments + bias: issued FIRST (L2-resident, latency hides
    //      under the HBM staging loads below) ----
    short8 afrag[2][6];
    const short* wbase = Wp + (size_t)enc * 128 * 192;
#pragma unroll
    for (int hb = 0; hb < 2; ++hb)
#pragma unroll
        for (int s = 0; s < 6; ++s)
            afrag[hb][s] = *(const short8*)(wbase + (h0 + hb * 16 + n) * 192 + s * 32 + q * 8);

    float4 b1q[2];
#pragma unroll
    for (int hb = 0; hb < 2; ++hb)
        b1q[hb] = *(const float4*)(b1 + h0 + hb * 16 + q * 4);

    // ---- staging ----
    int sw  = tid >> 6;   // wave id = t-quarter
    int scc = tid & 63;   // channel
    {
        const float* srow = xb + (size_t)scc * FP + t0 + sw * 16;
        float4 f0 = *(const float4*)(srow + 0);
        float4 f1 = *(const float4*)(srow + 4);
        float4 f2 = *(const float4*)(srow + 8);
        float4 f3 = *(const float4*)(srow + 12);
        float vals[16] = { f0.x, f0.y, f0.z, f0.w,  f1.x, f1.y, f1.z, f1.w,
                           f2.x, f2.y, f2.z, f2.w,  f3.x, f3.y, f3.z, f3.w };
        bool allv = (t0 + 64) <= FF;
#pragma unroll
        for (int u = 0; u < 16; ++u) {
            float val = vals[u];
            if (!allv) val = (t0 + sw * 16 + u) < FF ? val : 0.0f;
            int tt = sw * 16 + u + 1;
            Xt[(tt * 64 + scc) ^ ((tt & 7) << 3)] = f2bf(val);
        }
        if (tid < 128) {                  // waves 0,1: halo columns (uniform branch)
            int hhal = tid >> 6;          // 0: t0-1 row, 1: t0+64 row
            int ht = hhal ? (t0 + 64) : (t0 - 1);
            int hts = ht < 0 ? 0 : (ht >= FF ? FF - 1 : ht);
            float v = xb[(size_t)scc * FP + hts];
            if (ht < 0 || ht >= FF) v = 0.0f;
            int tt = hhal ? 65 : 0;
            Xt[(tt * 64 + scc) ^ ((tt & 7) << 3)] = f2bf(v);
        }
    }

    // keep weight fragments computed & alive before the barrier
#pragma unroll
    for (int hb = 0; hb < 2; ++hb)
#pragma unroll
        for (int s = 0; s < 6; ++s)
            asm volatile("" :: "v"(afrag[hb][s]));

    __syncthreads();

    // acc starts at bias (MFMA C-in carries it through)
    floatx4 acc[2][4];
#pragma unroll
    for (int hb = 0; hb < 2; ++hb)
#pragma unroll
        for (int tb = 0; tb < 4; ++tb) {
            acc[hb][tb][0] = b1q[hb].x;
            acc[hb][tb][1] = b1q[hb].y;
            acc[hb][tb][2] = b1q[hb].z;
            acc[hb][tb][3] = b1q[hb].w;
        }

#pragma unroll
    for (int s = 0; s < 6; ++s) {
        int kap = s >> 1;
        int cbase = (s & 1) * 32 + q * 8;
#pragma unroll
        for (int tb = 0; tb < 4; ++tb) {
            int row = tb * 16 + n + kap;
            short8 bfrag = *(const short8*)(Xt + ((row * 64 + cbase) ^ ((row & 7) << 3)));
            acc[0][tb] = __builtin_amdgcn_mfma_f32_16x16x32_bf16(afrag[0][s], bfrag, acc[0][tb], 0, 0, 0);
            acc[1][tb] = __builtin_amdgcn_mfma_f32_16x16x32_bf16(afrag[1][s], bfrag, acc[1][tb], 0, 0, 0);
        }
    }

    const float SELU_S = 1.0507009873554805f;
    const float SELU_A = 1.6732632423543772f;
    int ebase = (enc * 64 + b) * 128;
    bool edge = (t0 == 0) || (t0 == 4096);
    bool allv = (t0 + 63) < FF;
    float hsum[2][4] = {{0.f,0.f,0.f,0.f},{0.f,0.f,0.f,0.f}};
#pragma unroll
    for (int hb = 0; hb < 2; ++hb) {
#pragma unroll
        for (int tb = 0; tb < 4; ++tb) {
            int t = t0 + tb * 16 + n;
            bool valid = t < FF;
#pragma unroll
            for (int r = 0; r < 4; ++r) {
                float val = acc[hb][tb][r];
                float y = SELU_S * (val > 0.0f ? val : SELU_A * (__expf(val) - 1.0f));
                if (!allv) y = valid ? y : 0.0f;
                hsum[hb][r] += y;
                if (edge) {
                    int h = h0 + hb * 16 + q * 4 + r;
                    if (t == 0)      e0[ebase + h] = y;
                    if (t == FF - 1) e1[ebase + h] = y;
                }
            }
        }
    }

#pragma unroll
    for (int off = 1; off < 16; off <<= 1)
#pragma unroll
        for (int hb = 0; hb < 2; ++hb)
#pragma unroll
            for (int r = 0; r < 4; ++r)
                hsum[hb][r] += __shfl_xor(hsum[hb][r], off, 64);

    if (n == 0) {
#pragma unroll
        for (int hb = 0; hb < 2; ++hb) {
            size_t idx = ((size_t)(tile * 2 + enc) * 64 + b) * 128 + h0 + hb * 16 + q * 4;
            *(float4*)(part + idx) = make_float4(hsum[hb][0], hsum[hb][1], hsum[hb][2], hsum[hb][3]);
        }
    }
}

// ---------------------------------------------------------------------------
// Kernel B2: conv2 (mean via endpoint algebra) + bias + softmax
// (round 3: wave-parallel final reduction instead of 1-thread serial loop)
// ---------------------------------------------------------------------------
__global__ __launch_bounds__(128) void k_head(const float* __restrict__ part,
                                              const float* __restrict__ e0,
                                              const float* __restrict__ e1,
                                              const float* __restrict__ wR2,
                                              const float* __restrict__ bR2,
                                              const float* __restrict__ wI2,
                                              const float* __restrict__ bI2,
                                              float* __restrict__ Cw)
{
    __shared__ float red[3][128];
    int b   = blockIdx.x;
    int enc = blockIdx.y;
    const float* w2 = enc ? wI2 : wR2;
    const float* b2 = enc ? bI2 : bR2;
    int h = threadIdx.x;
    float T = 0.0f;
    for (int t = 0; t < NT; ++t)
        T += part[((size_t)(t * 2 + enc) * 64 + b) * 128 + h];
    float e0v = e0[(enc * 64 + b) * 128 + h];
    float e1v = e1[(enc * 64 + b) * 128 + h];
#pragma unroll
    for (int nn = 0; nn < 3; ++nn) {
        const float* wp = w2 + (nn * 128 + h) * 3;
        red[nn][h] = wp[0] * (T - e1v) + wp[1] * T + wp[2] * (T - e0v);
    }
    __syncthreads();
    if (h < 64) {
        float lg[3];
#pragma unroll
        for (int nn = 0; nn < 3; ++nn) {
            float s = red[nn][h] + red[nn][h + 64];
#pragma unroll
            for (int off = 1; off < 64; off <<= 1)
                s += __shfl_xor(s, off, 64);
            lg[nn] = b2[nn] + s / 4097.0f;
        }
        if (h == 0) {
            float mx = fmaxf(lg[0], fmaxf(lg[1], lg[2]));
            float ex0 = __expf(lg[0] - mx);
            float ex1 = __expf(lg[1] - mx);
            float ex2 = __expf(lg[2] - mx);
            float den = ex0 + ex1 + ex2;
            Cw[(enc * 64 + b) * 3 + 0] = ex0 / den;
            Cw[(enc * 64 + b) * 3 + 1] = ex1 / den;
            Cw[(enc * 64 + b) * 3 + 2] = ex2 / den;
        }
    }
}

// ---------------------------------------------------------------------------
// Kernel C: P = fx*Kf -> inverse FFT (register radix-16^3) -> out row.
// ---------------------------------------------------------------------------
__global__ __launch_bounds__(256, 4) void k_irfft(const float* __restrict__ fxr,
                                                  const float* __restrict__ fxi,
                                                  const float* __restrict__ param,
                                                  const float* __restrict__ Cw,
                                                  float* __restrict__ out)
{
    __shared__ float2 lds[4352];
    int bc = blockIdx.x, b = bc >> 6, c = bc & 63, tid = threadIdx.x;
    float cr0 = Cw[b*3+0], cr1 = Cw[b*3+1], cr2 = Cw[b*3+2];
    float ci0 = Cw[192 + b*3+0], ci1 = Cw[192 + b*3+1], ci2 = Cw[192 + b*3+2];
    size_t row = (size_t)bc * FP;
    const float2* W0 = (const float2*)param + (size_t)(0*64 + c) * FF;
    const float2* W1 = (const float2*)param + (size_t)(1*64 + c) * FF;
    const float2* W2 = (const float2*)param + (size_t)(2*64 + c) * FF;

    for (int f = tid; f <= 4096; f += 256) {
        float2 w0 = W0[f], w1 = W1[f], w2 = W2[f];
        float kr = cr0*w0.x + cr1*w1.x + cr2*w2.x;
        float ki = ci0*w0.y + ci1*w1.y + ci2*w2.y;
        float fr = fxr[row + f], fi = fxi[row + f];
        lds[f] = make_float2(fr*kr - fi*ki, fr*ki + fi*kr);
    }
    __syncthreads();

    const float COSJ[16] = COSJ_INIT;
    const float SINJ[16] = SINJ_INIT;
    float2 v[16];
    float sA, cA; __sincosf(3.14159265358979f * (float)tid * (1.0f/4096.0f), &sA, &cA);
#pragma unroll
    for (int j = 0; j < 16; ++j) {
        int m = tid + 256*j;
        if (m == 0) {
            float p0 = lds[0].x, pn = lds[4096].x;
            v[j] = make_float2(0.5f*(p0 + pn), 0.5f*(p0 - pn));
        } else {
            float2 p = lds[m], qq = lds[4096 - m];
            float er = 0.5f*(p.x + qq.x), ei = 0.5f*(p.y - qq.y);
            float dr = 0.5f*(p.x - qq.x), di = 0.5f*(p.y + qq.y);
            float cp = cA*COSJ[j] - sA*SINJ[j];
            float sp = sA*COSJ[j] + cA*SINJ[j];
            float zor = dr*cp - di*sp;
            float zoi = dr*sp + di*cp;
            v[j] = make_float2(er - zoi, ei + zor);
        }
    }
    __syncthreads();
    fft4096_regs<1>(v, lds, tid);

    const float S = 0.02209708691207961f;  // sqrt(8192)/4096
    float2* orow = (float2*)(out + (size_t)bc * LL);
#pragma unroll
    for (int j = 0; j < 16; ++j) {
        float2 z = v[j];
        orow[tid + 256*j] = make_float2(S*z.x, S*z.y);
    }
}

// ---------------------------------------------------------------------------
extern "C" void kernel_launch(void* const* d_in, const int* in_sizes, int n_in,
                              void* d_out, int out_size, void* d_ws, size_t ws_size,
                              hipStream_t stream)
{
    (void)in_sizes; (void)n_in; (void)out_size; (void)ws_size;
    const float* x   = (const float*)d_in[0];
    const float* prm = (const float*)d_in[1];
    const float* wR1 = (const float*)d_in[2];
    const float* bR1 = (const float*)d_in[3];
    const float* wR2 = (const float*)d_in[4];
    const float* bR2 = (const float*)d_in[5];
    const float* wI1 = (const float*)d_in[6];
    const float* bI1 = (const float*)d_in[7];
    const float* wI2 = (const float*)d_in[8];
    const float* bI2 = (const float*)d_in[9];
    float* out = (float*)d_out;
    float* ws  = (float*)d_ws;

    size_t o = 0;
    float* fxr  = ws + o; o += (size_t)BB * CCH * FP;
    float* fxi  = ws + o; o += (size_t)BB * CCH * FP;
    float* part = ws + o; o += (size_t)NT * 2 * 64 * 128;
    float* e0   = ws + o; o += 2 * 64 * 128;
    float* e1   = ws + o; o += 2 * 64 * 128;
    float* Cw   = ws + o; o += 2 * 64 * 4;
    short* Wp   = (short*)(ws + o); o += (size_t)2 * 128 * 192 / 2;

    k_rfft<<<dim3(4096), dim3(256), 0, stream>>>(x, fxr, fxi);
    k_pack<<<dim3((2 * 128 * 192 + 255) / 256), dim3(256), 0, stream>>>(wR1, wI1, Wp);
    k_conv_mfma<<<dim3(NT, 64, 2), dim3(256), 0, stream>>>(fxr, fxi, Wp, bR1, bI1,
                                                           part, e0, e1);
    k_head<<<dim3(64, 2), dim3(128), 0, stream>>>(part, e0, e1, wR2, bR2, wI2, bI2, Cw);
    k_irfft<<<dim3(4096), dim3(256), 0, stream>>>(fxr, fxi, prm, Cw, out);
}